// Round 5
// baseline (87.688 us; speedup 1.0000x reference)
//
#include <hip/hip_runtime.h>

// maTransformerBlock fused kernel for MI355X (gfx950) — R4
//
// Shuffle algebra: with output batch b' = k*1024 + j (k in [0,32), j in [0,1024)):
//   source batch = 32 j + n', chunk = k.
// => block j handles source batches 32j..32j+31 and output batches {k*1024 + j}.
//
// R4: conv reads its 19-float sliding windows DIRECTLY from global (L1/L2
// absorb the 1.48x neighbor overlap; HBM traffic unchanged). This deletes the
// 40KB LDS stage buffer, 17 of 18 barriers, and all staging bookkeeping.
// Conv weights have wave-uniform indices -> scalar loads (SGPR FMA operand).
// LDS = 33.8KB -> 4 blocks/CU, all 1024 blocks resident simultaneously.

constexpr int NB       = 32;    // source batches per block
constexpr int THREADS  = 256;
constexpr int NBLOCKS  = 1024;
constexpr int PSTRIDE4 = 33;    // attn plane stride in float4 (odd -> bank spread)

__global__ __launch_bounds__(THREADS, 4)
void fused_matx(const float* __restrict__ dna,
                const float* __restrict__ prot,
                const float* __restrict__ wdna,
                const float* __restrict__ wprot,
                const float* __restrict__ wlin,
                const float* __restrict__ blin,
                float* __restrict__ out)
{
    __shared__ float4 s_d4[NB * PSTRIDE4];   // [row r][chunk ob] relu(conv(dna))  16896 B
    __shared__ float4 s_p4[NB * PSTRIDE4];   // [row q][chunk ob] relu(conv(prot)) 16896 B

    const int tid = threadIdx.x;
    const int j   = blockIdx.x;

    const int cs = tid >> 3;      // source-batch slot 0..31
    const int xb = tid & 7;       // x-block 0..7 (12 conv outputs each)

    // ================= DNA conv: 4 channels, direct from global =================
    float dacc[12];
#pragma unroll
    for (int o = 0; o < 12; ++o) dacc[o] = 0.f;

    {
        const float* drow = dna + (size_t)(j * NB + cs) * 412 + 12 * xb;  // 4*103/batch
#pragma unroll
        for (int c = 0; c < 4; ++c) {
            float in[19];
#pragma unroll
            for (int t = 0; t < 19; ++t) in[t] = drow[c * 103 + t];
#pragma unroll
            for (int f = 0; f < 8; ++f) {
                const float w = wdna[c * 8 + f];      // uniform -> SGPR
#pragma unroll
                for (int o = 0; o < 12; ++o)
                    dacc[o] = fmaf(in[o + f], w, dacc[o]);
            }
        }
    }
#pragma unroll
    for (int u = 0; u < 4; ++u) {                     // store relu'd dna conv
        float4 v;
        v.x = fmaxf(dacc[3*u+0], 0.f);
        v.y = fmaxf(dacc[3*u+1], 0.f);
        v.z = fmaxf(dacc[3*u+2], 0.f);
        v.w = 0.f;
        s_d4[cs * PSTRIDE4 + 4 * xb + u] = v;
    }

    // ================= PROT conv: 21 channels, direct from global =================
    float pacc[12];
#pragma unroll
    for (int o = 0; o < 12; ++o) pacc[o] = 0.f;

    {
        const float* prow = prot + (size_t)(j * NB + cs) * 2163 + 12 * xb;  // 21*103/batch
#pragma unroll
        for (int c = 0; c < 21; ++c) {
            float in[19];
#pragma unroll
            for (int t = 0; t < 19; ++t) in[t] = prow[c * 103 + t];
#pragma unroll
            for (int f = 0; f < 8; ++f) {
                const float w = wprot[c * 8 + f];     // uniform -> SGPR
#pragma unroll
                for (int o = 0; o < 12; ++o)
                    pacc[o] = fmaf(in[o + f], w, pacc[o]);
            }
        }
    }
#pragma unroll
    for (int u = 0; u < 4; ++u) {                     // store relu'd prot conv
        float4 v;
        v.x = fmaxf(pacc[3*u+0], 0.f);
        v.y = fmaxf(pacc[3*u+1], 0.f);
        v.z = fmaxf(pacc[3*u+2], 0.f);
        v.w = 0.f;
        s_p4[cs * PSTRIDE4 + 4 * xb + u] = v;
    }

    __syncthreads();   // the only barrier

    // ================= attention (32x32, d=3) + linear =================
    const float scale = 0.5773502691896258f;   // 1/sqrt(3)
    const int qr   = tid & 31;                  // query row
    const int obHi = tid >> 5;                  // 2 distinct ob per wave -> LDS broadcast
    const float wl00 = wlin[3 * qr + 0], wl01 = wlin[3 * qr + 1], wl02 = wlin[3 * qr + 2];
    const float wl10 = wlin[96 + 3 * qr + 0], wl11 = wlin[96 + 3 * qr + 1], wl12 = wlin[96 + 3 * qr + 2];
    const float bl0 = blin[0], bl1 = blin[1];

    for (int it = 0; it < 4; ++it) {
        const int ob = obHi * 4 + it;          // chunk k = output batch ob*1024 + j
        const float4 qv = s_p4[qr * PSTRIDE4 + ob];

        float lg[32];
        float mx = -1e30f;
#pragma unroll
        for (int r = 0; r < 32; ++r) {         // one broadcast ds_read_b128 per key
            float4 dv = s_d4[r * PSTRIDE4 + ob];
            float l = fmaf(qv.x, dv.x, fmaf(qv.y, dv.y, qv.z * dv.z)) * scale;
            lg[r] = l;
            mx = fmaxf(mx, l);
        }
        float sum = 0.f;
#pragma unroll
        for (int r = 0; r < 32; ++r) {
            float e = __expf(lg[r] - mx);
            lg[r] = e;
            sum += e;
        }
        const float inv = 1.f / sum;
        float v0 = 0.f, v1 = 0.f, v2 = 0.f;
#pragma unroll
        for (int r = 0; r < 32; ++r) {
            float4 dv = s_d4[r * PSTRIDE4 + ob];
            v0 = fmaf(lg[r], dv.x, v0);
            v1 = fmaf(lg[r], dv.y, v1);
            v2 = fmaf(lg[r], dv.z, v2);
        }
        v0 *= inv; v1 *= inv; v2 *= inv;

        // linear: out2[oi] = sum_{q,c} wl[oi][3q+c] * val[q][c]; reduce over 32 q-lanes
        float o0 = wl00 * v0 + wl01 * v1 + wl02 * v2;
        float o1 = wl10 * v0 + wl11 * v1 + wl12 * v2;
#pragma unroll
        for (int m = 16; m >= 1; m >>= 1) {    // stays within each 32-lane half
            o0 += __shfl_xor(o0, m);
            o1 += __shfl_xor(o1, m);
        }
        if (qr == 0) {
            const int bp = (ob << 10) + j;     // output batch index
            float2 res;
            res.x = o0 + bl0;
            res.y = o1 + bl1;
            *reinterpret_cast<float2*>(&out[(size_t)bp * 2]) = res;
        }
    }
}

extern "C" void kernel_launch(void* const* d_in, const int* in_sizes, int n_in,
                              void* d_out, int out_size, void* d_ws, size_t ws_size,
                              hipStream_t stream) {
    const float* dna   = (const float*)d_in[0];
    const float* prot  = (const float*)d_in[1];
    const float* wdna  = (const float*)d_in[2];
    const float* wprot = (const float*)d_in[3];
    const float* wlin  = (const float*)d_in[4];
    const float* blin  = (const float*)d_in[5];
    float* out = (float*)d_out;

    fused_matx<<<NBLOCKS, THREADS, 0, stream>>>(dna, prot, wdna, wprot, wlin, blin, out);
}

// Round 6
// 68.350 us; speedup vs baseline: 1.2829x; 1.2829x over previous
//
#include <hip/hip_runtime.h>

// maTransformerBlock fused kernel for MI355X (gfx950) — R5
//
// Shuffle algebra: with output batch b' = k*1024 + j (k in [0,32), j in [0,1024)):
//   source batch = 32 j + n', chunk = k.
// => block j handles source batches 32j..32j+31 and output batches {k*1024 + j}.
//
// R5 structure:
//  - 25 single-channel stage phases (4 dna + 21 prot), LDS rows padded to 132
//    floats so staging index math is pure shifts (s = i>>7, p = i&127).
//  - T14 register ping-pong prefetch (pfA/pfB, 16 floats each): phase p+1's
//    global loads drain while phase p computes.
//  - q (prot conv result) stays IN REGISTERS: attn thread (cs,xb) handles
//    (qr=cs, ob=4xb+it), matching its own conv outputs. No s_p4 plane.
//  - d-plane layout [ob][slot = cs+xb] stride 40: attention ds_read_b128 is
//    base + compile-time immediate, bank-group (xb+r)%8 => conflict-free.
//  - single-pass softmax w/o max subtraction (logits bounded << 88 in f32).
//  - LDS 38.4 KB -> 4 blocks/CU; grid 1024 = 4 x 256 CUs fully resident.

constexpr int NB      = 32;
constexpr int THREADS = 256;
constexpr int NBLOCKS = 1024;

__global__ __launch_bounds__(THREADS, 4)
void fused_matx(const float* __restrict__ dna,
                const float* __restrict__ prot,
                const float* __restrict__ wdna,
                const float* __restrict__ wprot,
                const float* __restrict__ wlin,
                const float* __restrict__ blin,
                float* __restrict__ out)
{
    __shared__ __align__(16) float s_stage[NB * 132];  // 16896 B, one channel, padded rows
    __shared__ float4 s_d4[32 * 40];                   // 20480 B, [ob][slot=cs+xb]
    __shared__ float2 s_red[128];                      // 1024 B, [wave][ob] partials

    const int tid = threadIdx.x;
    const int j   = blockIdx.x;

    const int cs = tid >> 3;        // conv row (source batch slot) 0..31
    const int xb = tid & 7;         // conv x-block 0..7 (12 outputs)

    // staging geometry: slot i = tid + 256k in [0,4096); s = i>>7, p = i&127
    const int pp  = tid & 127;
    const int s0  = tid >> 7;
    const int ppc = (pp < 103) ? pp : 102;     // clamp: lanes p>=103 load valid dup data
    const int a0d = s0 * 412  + ppc;
    const int a0p = s0 * 2163 + ppc;
    const int l0  = s0 * 132  + pp;            // LDS write slot (pad region p>=103 unused)

    const float* dbase = dna  + (size_t)j * NB * 412;   // 4*103 floats/batch
    const float* pbase = prot + (size_t)j * NB * 2163;  // 21*103 floats/batch

    float pfA[16], pfB[16];

    auto pf_dna = [&](int c, float (&pf)[16]) {
        const float* pa = dbase + c * 103 + a0d;
#pragma unroll
        for (int k = 0; k < 16; ++k) pf[k] = pa[824 * k];     // 824 = 2*412
    };
    auto pf_prot = [&](int c, float (&pf)[16]) {
        const float* pa = pbase + c * 103 + a0p;
#pragma unroll
        for (int k = 0; k < 16; ++k) pf[k] = pa[4326 * k];    // 4326 = 2*2163
    };
    auto wr = [&](float (&pf)[16]) {
#pragma unroll
        for (int k = 0; k < 16; ++k) s_stage[l0 + 264 * k] = pf[k];  // imm offsets
    };
    auto conv8 = [&](const float* __restrict__ wsrc, int c, float (&acc)[12]) {
        float w[8];
#pragma unroll
        for (int f = 0; f < 8; ++f) w[f] = wsrc[c * 8 + f];   // uniform -> scalar
        float in[20];
        const float4* sp = reinterpret_cast<const float4*>(&s_stage[cs * 132 + 12 * xb]);
#pragma unroll
        for (int u = 0; u < 5; ++u) {                          // 5 aligned ds_read_b128
            float4 v = sp[u];
            in[4*u+0] = v.x; in[4*u+1] = v.y; in[4*u+2] = v.z; in[4*u+3] = v.w;
        }
#pragma unroll
        for (int f = 0; f < 8; ++f)
#pragma unroll
            for (int o = 0; o < 12; ++o)
                acc[o] = fmaf(in[o + f], w[f], acc[o]);
    };

    // ================= DNA: 4 pipelined phases =================
    float dacc[12];
#pragma unroll
    for (int o = 0; o < 12; ++o) dacc[o] = 0.f;

    pf_dna(0, pfA);
    wr(pfA); pf_dna(1, pfB); __syncthreads(); conv8(wdna, 0, dacc); __syncthreads();
    wr(pfB); pf_dna(2, pfA); __syncthreads(); conv8(wdna, 1, dacc); __syncthreads();
    wr(pfA); pf_dna(3, pfB); __syncthreads(); conv8(wdna, 2, dacc); __syncthreads();
    wr(pfB); pf_prot(0, pfA); __syncthreads(); conv8(wdna, 3, dacc); __syncthreads();

    // store relu'd dna conv: row cs of chunk ob=4xb+u at slot cs+xb (bijective per ob)
#pragma unroll
    for (int u = 0; u < 4; ++u) {
        float4 v;
        v.x = fmaxf(dacc[3*u+0], 0.f);
        v.y = fmaxf(dacc[3*u+1], 0.f);
        v.z = fmaxf(dacc[3*u+2], 0.f);
        v.w = 0.f;
        s_d4[(4 * xb + u) * 40 + cs + xb] = v;
    }

    // ================= PROT: 21 pipelined phases =================
    float pacc[12];
#pragma unroll
    for (int o = 0; o < 12; ++o) pacc[o] = 0.f;

    for (int q = 0; q < 20; q += 2) {
        wr(pfA); pf_prot(q + 1, pfB); __syncthreads(); conv8(wprot, q,     pacc); __syncthreads();
        wr(pfB); pf_prot(q + 2, pfA); __syncthreads(); conv8(wprot, q + 1, pacc); __syncthreads();
    }
    wr(pfA); __syncthreads(); conv8(wprot, 20, pacc);
    // pacc stays in registers; s_d4 was published before many earlier barriers.

    // ================= attention (32x32, d=3) + linear =================
    // thread (cs,xb): qr = cs (own pacc), ob = 4xb+it. d-reads: base + imm only.
    const float4* dp = s_d4 + 161 * xb;        // (4xb)*40 + xb
    float wl0[3], wl1[3];
#pragma unroll
    for (int t = 0; t < 3; ++t) {
        wl0[t] = wlin[3 * cs + t];
        wl1[t] = wlin[96 + 3 * cs + t];
    }
    const float escale = 0.5773502691896258f;  // 1/sqrt(3); exp(l*escale) bounded << 88

#pragma unroll
    for (int it = 0; it < 4; ++it) {
        const float q0 = fmaxf(pacc[3*it+0], 0.f);
        const float q1 = fmaxf(pacc[3*it+1], 0.f);
        const float q2 = fmaxf(pacc[3*it+2], 0.f);

        float sum = 0.f, v0 = 0.f, v1 = 0.f, v2 = 0.f;
#pragma unroll
        for (int r = 0; r < 32; ++r) {         // conflict-free broadcast b128 reads
            float4 dv = dp[40 * it + r];       // = s_d4[ob*40 + (r+xb)] = row r of ob
            float l = fmaf(q0, dv.x, fmaf(q1, dv.y, q2 * dv.z));
            float e = __expf(l * escale);
            sum += e;
            v0 = fmaf(e, dv.x, v0);
            v1 = fmaf(e, dv.y, v1);
            v2 = fmaf(e, dv.z, v2);
        }
        const float inv = 1.f / sum;
        float o0 = (wl0[0] * v0 + wl0[1] * v1 + wl0[2] * v2) * inv;
        float o1 = (wl1[0] * v0 + wl1[1] * v1 + wl1[2] * v2) * inv;
        // reduce over the 8 cs rows in this wave (lane bits 3..5)
        o0 += __shfl_xor(o0, 8);  o1 += __shfl_xor(o1, 8);
        o0 += __shfl_xor(o0, 16); o1 += __shfl_xor(o1, 16);
        o0 += __shfl_xor(o0, 32); o1 += __shfl_xor(o1, 32);
        if ((tid & 56) == 0)                   // one lane per (wave, xb)
            s_red[(tid >> 6) * 32 + 4 * xb + it] = make_float2(o0, o1);
    }
    __syncthreads();

    if (tid < 32) {                            // combine 4 wave-partials + bias, store
        float2 a = s_red[tid], b = s_red[32 + tid], c = s_red[64 + tid], d = s_red[96 + tid];
        float2 r;
        r.x = a.x + b.x + c.x + d.x + blin[0];
        r.y = a.y + b.y + c.y + d.y + blin[1];
        *reinterpret_cast<float2*>(&out[(size_t)((tid << 10) + j) * 2]) = r;
    }
}

extern "C" void kernel_launch(void* const* d_in, const int* in_sizes, int n_in,
                              void* d_out, int out_size, void* d_ws, size_t ws_size,
                              hipStream_t stream) {
    const float* dna   = (const float*)d_in[0];
    const float* prot  = (const float*)d_in[1];
    const float* wdna  = (const float*)d_in[2];
    const float* wprot = (const float*)d_in[3];
    const float* wlin  = (const float*)d_in[4];
    const float* blin  = (const float*)d_in[5];
    float* out = (float*)d_out;

    fused_matx<<<NBLOCKS, THREADS, 0, stream>>>(dna, prot, wdna, wprot, wlin, blin, out);
}